// Round 7
// baseline (232.037 us; speedup 1.0000x reference)
//
#include <hip/hip_runtime.h>

// LIF neuron over [T, B, C, H, W] = [8, 32, 128, 32, 32] fp32.
// V_new = V + (-V/TAU + x_t); spike = (V_new>=1) - (V_new<=-1); hard reset.
//
// R1-R3: single-chain version pinned at 82 us / 2.4 TB/s (one HBM latency
// per timestep per wave; scheduler refused to keep >1 load in flight).
// R4-R6: 4 independent columns per thread (strided by Q = n4/4) -> 4
// back-to-back loads + 4 stores per timestep per wave; kernel dropped off
// the top-5 (now < 82 us, ~70 us est). Poison fills calibrate the box at
// 6.5 TB/s writes -> headroom remains.
// R7: loads CACHED (input is freshly L3-resident from the harness restore
// blit; R1 showed 50% L3 fetch absorption), stores stay NT (output never
// re-read in timed region; don't evict input from L3).

#define T_STEPS 8

typedef float vfloat4 __attribute__((ext_vector_type(4)));

struct StepOut { float V; float o; };

__device__ __forceinline__ StepOut lif_step(float V, float x) {
    const float TAU = (float)(5.0 / 3.0);  // fp32, matches np cast
    // Replicate reference op order exactly: neg, IEEE divide, add, add.
    float dv = (-V) / TAU + x;
    float Vn = V + dv;
    float o = (Vn >= 1.0f ? 1.0f : 0.0f) - (Vn <= -1.0f ? 1.0f : 0.0f);
    StepOut r;
    r.o = o;
    r.V = (o == 0.0f) ? Vn : 0.0f;  // o is exactly -1/0/+1
    return r;
}

__device__ __forceinline__ vfloat4 lif_step4(vfloat4& V, vfloat4 xt) {
    StepOut a = lif_step(V.x, xt.x);
    StepOut b = lif_step(V.y, xt.y);
    StepOut c = lif_step(V.z, xt.z);
    StepOut d = lif_step(V.w, xt.w);
    vfloat4 Vn, o;
    Vn.x = a.V; Vn.y = b.V; Vn.z = c.V; Vn.w = d.V;
    o.x = a.o;  o.y = b.o;  o.z = c.o;  o.w = d.o;
    V = Vn;
    return o;
}

__global__ __launch_bounds__(256) void lif_kernel(const vfloat4* __restrict__ x,
                                                  vfloat4* __restrict__ out,
                                                  int n4) {
    const int Q = n4 >> 2;  // columns per chain-slot (n4 divisible by 4)
    int q = blockIdx.x * blockDim.x + threadIdx.x;
    if (q >= Q) return;

    const size_t s = (size_t)n4;
    const size_t i0 = (size_t)q;
    const size_t i1 = (size_t)q + (size_t)Q;
    const size_t i2 = (size_t)q + 2 * (size_t)Q;
    const size_t i3 = (size_t)q + 3 * (size_t)Q;

    vfloat4 Va = (vfloat4)(0.f);
    vfloat4 Vb = Va, Vc = Va, Vd = Va;

#pragma unroll
    for (int t = 0; t < T_STEPS; ++t) {
        const size_t base = (size_t)t * s;
        // 4 independent CACHED loads issued back-to-back.
        vfloat4 xa = x[base + i0];
        vfloat4 xb = x[base + i1];
        vfloat4 xc = x[base + i2];
        vfloat4 xd = x[base + i3];

        vfloat4 oa = lif_step4(Va, xa);
        vfloat4 ob = lif_step4(Vb, xb);
        vfloat4 oc = lif_step4(Vc, xc);
        vfloat4 od = lif_step4(Vd, xd);

        // NT stores: keep the write stream out of L2/L3.
        __builtin_nontemporal_store(oa, &out[base + i0]);
        __builtin_nontemporal_store(ob, &out[base + i1]);
        __builtin_nontemporal_store(oc, &out[base + i2]);
        __builtin_nontemporal_store(od, &out[base + i3]);
    }
}

extern "C" void kernel_launch(void* const* d_in, const int* in_sizes, int n_in,
                              void* d_out, int out_size, void* d_ws, size_t ws_size,
                              hipStream_t stream) {
    const float* x = (const float*)d_in[0];
    float* out = (float*)d_out;

    int total = in_sizes[0];            // T*B*C*H*W = 33554432
    int n = total / T_STEPS;            // spatial elements per timestep
    int n4 = n / 4;                     // float4 groups = 1048576
    int Q = n4 / 4;                     // threads = 262144

    dim3 block(256);
    dim3 grid((Q + block.x - 1) / block.x);  // 1024 blocks
    lif_kernel<<<grid, block, 0, stream>>>((const vfloat4*)x, (vfloat4*)out, n4);
}